// Round 18
// baseline (180.786 us; speedup 1.0000x reference)
//
#include <hip/hip_runtime.h>
#include <math.h>
#include <stdint.h>

// Problem constants
#define TT 4
#define BB 16
#define CC 256
#define NN 1024
#define NT 8         // spatial positions per block (cols = 4t * 8n = 32)
#define EPSF 1e-5f
// Rescue margin: 3-product q/k GEMM error sigma ~3e-6; 6e-5 = ~14 sigma
// (validated R13-R17). Margin-flagged decisions recompute with the exact
// fp32 chain (bit-identical to reference) -> final spikes exact regardless.
#define EPS_R 6e-5f

typedef __attribute__((ext_vector_type(8))) short short8;  // 8 bf16 (4 VGPR)
typedef __attribute__((ext_vector_type(4))) float f32x4;
#define MFMA __builtin_amdgcn_mfma_f32_16x16x32_bf16

// LDS: 2 X planes (hi, mid) + fp32 staging scratch = 38400 B
// -> 4 blocks/CU (153600 <= 160K), 32 waves/CU target.
#define XCH 528           // X-plane chunk stride: 512 + 16 bank-shift
#define XPL 16896         // X plane = 32 chunks * 528
#define LDS_X 0
#define LDS_XF 33792      // scratch: 32c * 36dw * 4B = 4608
#define LDS_TOT 38400

// bf16 split helpers (RNE). v == hi + mid (+lo) exactly per plane.
__device__ __forceinline__ uint32_t f2bf(float x) {
  const uint32_t u = __float_as_uint(x);
  return (u + 0x7FFFu + ((u >> 16) & 1u)) >> 16;
}
__device__ __forceinline__ float bf2f(uint32_t b) { return __uint_as_float(b << 16); }

// ---------------- weight pre-split kernel (layout identical R10-R17) --------
// ws bytes: mat*393216 + p*131072 + ot*8192 + kk*1024 + lane*16.
// Lane l: w_plane[o = ot*16 + (l&15)][k = kk*32 + (l>>4)*8 .. +8]
__global__ __launch_bounds__(256)
void wsplit2(const float* __restrict__ qw, const float* __restrict__ kw,
             const float* __restrict__ pw, uint16_t* __restrict__ ws) {
  const int gid = blockIdx.x * 256 + threadIdx.x;   // 24576 threads
  const int mat = gid >> 13;
  const int ot  = (gid >> 9) & 15;
  const int kk  = (gid >> 6) & 7;
  const int l   = gid & 63;
  const float* w = (mat == 0 ? qw : (mat == 1 ? kw : pw));
  const int o  = ot * 16 + (l & 15);
  const int k0 = kk * 32 + (l >> 4) * 8;
  uint16_t ph[8], pm[8], pl[8];
  #pragma unroll
  for (int j = 0; j < 8; ++j) {
    const float v = w[(size_t)o * CC + k0 + j];
    const uint32_t bh = f2bf(v);
    const float r1 = v - bf2f(bh);       // exact
    const uint32_t bm = f2bf(r1);
    const float r2 = r1 - bf2f(bm);      // exact
    ph[j] = (uint16_t)bh; pm[j] = (uint16_t)bm; pl[j] = (uint16_t)f2bf(r2);
  }
  const size_t base = ((size_t)mat * 3 * 65536) + ((size_t)ot * 4096) +
                      kk * 512 + l * 8;            // uint16 units
  *(uint4*)(ws + base)          = *(const uint4*)ph;
  *(uint4*)(ws + base + 65536)  = *(const uint4*)pm;
  *(uint4*)(ws + base + 131072) = *(const uint4*)pl;
}

// LIF (tau=2, hard reset) with decision-margin tracking.
__device__ __forceinline__ void lif4m(float q0, float q1, float q2, float q3,
                                      float th, float s[4], float& mg) {
  const float qq[4] = {q0, q1, q2, q3};
  float v = 0.f;
  #pragma unroll
  for (int t = 0; t < 4; ++t) {
    const float h = v + (qq[t] - v) * 0.5f;
    const float d = h - th;
    mg = fminf(mg, fabsf(d));
    const bool f = d >= 0.f;
    s[t] = f ? 1.f : 0.f;
    v = f ? 0.f : h;
  }
}

// Cooperative exact rescue chain (q/k): 64 lanes (dup x2) recompute channel o
// for (t = (lane>>3)&3, col = n0 + (lane&7)) with the exact ascending-c fmaf
// chain on exact fp32 x from global (coalesced across the 8 n-lanes).
// Validated mechanism in R17 (absmax 0.0, no tail).
__device__ __forceinline__ float coop_chain(const float* __restrict__ wrow,
                                            const float* __restrict__ x,
                                            int b, int n0, int lane) {
  const float* xg = x + (size_t)((((lane >> 3) & 3)) * BB + b) * CC * NN +
                    n0 + (lane & 7);
  float s = 0.f;
  #pragma unroll 8
  for (int c = 0; c < CC; ++c) s = fmaf(wrow[c], xg[(size_t)c * NN], s);
  return s;
}

// Exact-chain rescue (proj): x_one is binary, exact in LDS plane 0.
__device__ __forceinline__ void rescue1(const float* __restrict__ wrow,
                                        const char* lds, int n, float sv[4]) {
  #pragma unroll
  for (int t = 0; t < 4; ++t) sv[t] = 0.f;
  #pragma unroll 1
  for (int c8 = 0; c8 < 32; ++c8) {
    const float4 wa = *(const float4*)(wrow + c8 * 8);
    const float4 wb = *(const float4*)(wrow + c8 * 8 + 4);
    const float wl_[8] = {wa.x, wa.y, wa.z, wa.w, wb.x, wb.y, wb.z, wb.w};
    #pragma unroll
    for (int t = 0; t < 4; ++t) {
      const short8 h = *(const short8*)(lds + LDS_X + c8 * XCH +
                                        (t * 8 + n) * 16);
      float s = sv[t];
      #pragma unroll
      for (int j = 0; j < 8; ++j)
        s = fmaf(wl_[j], bf2f((uint16_t)h[j]), s);
      sv[t] = s;
    }
  }
}

// 512 thr = 8 waves; 4 blocks/CU by LDS -> up to 32 waves/CU.
// Wave wv = head wv, iterating o-tiles {2wv, 2wv+1}; head reduce in-wave.
// Cols = t*8+n: lane holds t=(ln>>3) and t+2; shfl_xor(8) pairs assemble
// the 4-t LIF chain (bit-exact copies). Products {wm*xh, wh*xm, wh*xh}
// per accumulator, identical order to R13-R17 -> spikes bit-exact.
__global__ __launch_bounds__(512, 4)
void pushpull_mfma11(const float* __restrict__ x,
                     const float* __restrict__ q_w, const float* __restrict__ q_gamma,
                     const float* __restrict__ q_beta, const float* __restrict__ q_mean,
                     const float* __restrict__ q_var,
                     const float* __restrict__ k_w, const float* __restrict__ k_gamma,
                     const float* __restrict__ k_beta, const float* __restrict__ k_mean,
                     const float* __restrict__ k_var,
                     const float* __restrict__ proj_w, const float* __restrict__ proj_b,
                     const float* __restrict__ p_gamma, const float* __restrict__ p_beta,
                     const float* __restrict__ p_mean, const float* __restrict__ p_var,
                     const uint16_t* __restrict__ ws, float* __restrict__ out) {
  __shared__ __align__(16) char lds[LDS_TOT];

  const int tid  = threadIdx.x;
  const int bid  = (int)blockIdx.x;
  const int lid  = ((bid & 7) << 8) | (bid >> 3);   // bijective (2048 = 8*256)
  const int b    = lid >> 7;
  const int n0   = (lid & 127) * NT;
  const int lane = tid & 63;
  const int ln   = lane & 15;
  const int n    = lane & 7;
  const int tl   = (lane >> 3) & 1;
  const int g    = (lane >> 4) & 3;
  const int wv   = tid >> 6;           // wave = head

  // ---- stage x in 8 passes of 32 channels: fp32 -> {hi, mid} planes ----
  float* xf = (float*)(lds + LDS_XF);
  #pragma unroll 1
  for (int ps = 0; ps < 8; ++ps) {
    if (tid < 256) {                   // 32c x 4t x 2 float4 = 256 loads
      const int cl = tid >> 3, t = (tid >> 1) & 3, n4 = (tid & 1) * 4;
      const float4 v = *(const float4*)(
          x + ((size_t)(t * BB + b) * CC + ps * 32 + cl) * NN + n0 + n4);
      *(float4*)(xf + cl * 36 + t * 8 + n4) = v;
    }
    __syncthreads();
    if (tid < 128) {                   // 4 chunks x 32 cols
      const int chL = tid >> 5, col = tid & 31;
      uint16_t ph[8], pm[8];
      #pragma unroll
      for (int j = 0; j < 8; ++j) {
        const float v = xf[(chL * 8 + j) * 36 + col];
        const uint32_t bh = f2bf(v);
        pm[j] = (uint16_t)f2bf(v - bf2f(bh));
        ph[j] = (uint16_t)bh;
      }
      const int ca = (ps * 4 + chL) * XCH + col * 16;
      *(uint4*)(lds + LDS_X + ca) = *(const uint4*)ph;
      *(uint4*)(lds + LDS_X + XPL + ca) = *(const uint4*)pm;
    }
    __syncthreads();
  }

  const char* wq = (const char*)ws;                       // q planes
  const char* wk = (const char*)ws + 393216;              // k planes
  const char* wp = (const char*)ws + 786432;              // proj planes

  float dsum[4] = {0.f, 0.f, 0.f, 0.f};
  unsigned kb0 = 0u, kb1 = 0u;         // k-spike bits per o-tile, bit r*4+t

  // ====== fused q + k per o-tile (2 per wave), 3 products each ======
  auto qk_tile = [&](const int ot, unsigned& kbout) {
    f32x4 aq[2], ak[2];
    aq[0] = aq[1] = ak[0] = ak[1] = (f32x4)0.f;
    #pragma unroll 1
    for (int kk = 0; kk < 8; ++kk) {
      const size_t f0 = (size_t)ot * 8192 + (size_t)kk * 1024 + (size_t)lane * 16;
      const short8 fq0 = *(const short8*)(wq + f0);            // hi
      const short8 fq1 = *(const short8*)(wq + 131072 + f0);   // mid
      const short8 fk0 = *(const short8*)(wk + f0);
      const short8 fk1 = *(const short8*)(wk + 131072 + f0);
      __builtin_amdgcn_s_setprio(1);
      #pragma unroll
      for (int nt = 0; nt < 2; ++nt) {
        const int boff = (kk * 4 + g) * XCH + (nt * 16 + ln) * 16;
        const short8 b0 = *(const short8*)(lds + LDS_X + boff);
        const short8 b1 = *(const short8*)(lds + LDS_X + XPL + boff);
        aq[nt] = MFMA(fq1, b0, aq[nt], 0, 0, 0);
        aq[nt] = MFMA(fq0, b1, aq[nt], 0, 0, 0);
        aq[nt] = MFMA(fq0, b0, aq[nt], 0, 0, 0);
        ak[nt] = MFMA(fk1, b0, ak[nt], 0, 0, 0);
        ak[nt] = MFMA(fk0, b1, ak[nt], 0, 0, 0);
        ak[nt] = MFMA(fk0, b0, ak[nt], 0, 0, 0);
      }
      __builtin_amdgcn_s_setprio(0);
    }
    // ---- q epilogue: BN + push/pull LIF (+coop rescue) -> dsum ----
    #pragma unroll
    for (int r = 0; r < 4; ++r) {
      const int o = ot * 16 + g * 4 + r;
      const float inv = q_gamma[o] / sqrtf(q_var[o] + EPSF);
      const float mn = q_mean[o], bt = q_beta[o];
      const float own0 = aq[0][r], own1 = aq[1][r];
      const float oth0 = __shfl_xor(own0, 8), oth1 = __shfl_xor(own1, 8);
      float qv[4];
      qv[0] = ((tl ? oth0 : own0) - mn) * inv + bt;
      qv[1] = ((tl ? own0 : oth0) - mn) * inv + bt;
      qv[2] = ((tl ? oth1 : own1) - mn) * inv + bt;
      qv[3] = ((tl ? own1 : oth1) - mn) * inv + bt;
      float se[4], si[4], mg = 1e30f;
      lif4m(qv[0], qv[1], qv[2], qv[3], 1.0f, se, mg);
      lif4m(-qv[0], -qv[1], -qv[2], -qv[3], 1.0f, si, mg);
      const bool fl = (mg < EPS_R);
      const unsigned long long bal = __ballot(fl);
      if (__builtin_expect(bal != 0ull, 0)) {
        #pragma unroll 1
        for (int g2 = 0; g2 < 4; ++g2) {
          if (!((bal >> (g2 * 16)) & 0xFFFFull)) continue;
          const int o2 = ot * 16 + g2 * 4 + r;
          const float s = coop_chain(q_w + (size_t)o2 * CC, x, b, n0, lane);
          float qt[4];
          qt[0] = __shfl(s, n);      qt[1] = __shfl(s, 8 + n);
          qt[2] = __shfl(s, 16 + n); qt[3] = __shfl(s, 24 + n);
          if (g == g2 && fl) {
            float q2v[4];
            #pragma unroll
            for (int t = 0; t < 4; ++t) q2v[t] = (qt[t] - mn) * inv + bt;
            float m2 = 1e30f;
            lif4m(q2v[0], q2v[1], q2v[2], q2v[3], 1.0f, se, m2);
            lif4m(-q2v[0], -q2v[1], -q2v[2], -q2v[3], 1.0f, si, m2);
          }
        }
      }
      #pragma unroll
      for (int t = 0; t < 4; ++t) dsum[t] += se[t] - si[t];   // exact ints
    }
    // ---- k epilogue: BN + LIF (+coop rescue) -> spike bits ----
    #pragma unroll
    for (int r = 0; r < 4; ++r) {
      const int o = ot * 16 + g * 4 + r;
      const float inv = k_gamma[o] / sqrtf(k_var[o] + EPSF);
      const float mn = k_mean[o], bt = k_beta[o];
      const float own0 = ak[0][r], own1 = ak[1][r];
      const float oth0 = __shfl_xor(own0, 8), oth1 = __shfl_xor(own1, 8);
      float kv[4];
      kv[0] = ((tl ? oth0 : own0) - mn) * inv + bt;
      kv[1] = ((tl ? own0 : oth0) - mn) * inv + bt;
      kv[2] = ((tl ? oth1 : own1) - mn) * inv + bt;
      kv[3] = ((tl ? own1 : oth1) - mn) * inv + bt;
      float sk[4], mg = 1e30f;
      lif4m(kv[0], kv[1], kv[2], kv[3], 1.0f, sk, mg);
      const bool fl = (mg < EPS_R);
      const unsigned long long bal = __ballot(fl);
      if (__builtin_expect(bal != 0ull, 0)) {
        #pragma unroll 1
        for (int g2 = 0; g2 < 4; ++g2) {
          if (!((bal >> (g2 * 16)) & 0xFFFFull)) continue;
          const int o2 = ot * 16 + g2 * 4 + r;
          const float s = coop_chain(k_w + (size_t)o2 * CC, x, b, n0, lane);
          float kt[4];
          kt[0] = __shfl(s, n);      kt[1] = __shfl(s, 8 + n);
          kt[2] = __shfl(s, 16 + n); kt[3] = __shfl(s, 24 + n);
          if (g == g2 && fl) {
            float k2v[4];
            #pragma unroll
            for (int t = 0; t < 4; ++t) k2v[t] = (kt[t] - mn) * inv + bt;
            float m2 = 1e30f;
            lif4m(k2v[0], k2v[1], k2v[2], k2v[3], 1.0f, sk, m2);
          }
        }
      }
      #pragma unroll
      for (int t = 0; t < 4; ++t)
        kbout |= (sk[t] != 0.f) ? (1u << (r * 4 + t)) : 0u;
    }
  };
  qk_tile(wv * 2 + 0, kb0);
  qk_tile(wv * 2 + 1, kb1);

  // ---- head reduce: over the 4 g-groups (in-wave, exact ints) ----
  #pragma unroll
  for (int t = 0; t < 4; ++t) {
    float v = dsum[t];
    v += __shfl_xor(v, 16);
    v += __shfl_xor(v, 32);
    dsum[t] = v;
  }
  float at[4];
  {
    float mgd = 1e30f;
    lif4m(dsum[0], dsum[1], dsum[2], dsum[3], 0.5f, at, mgd);  // exact dyadics
  }

  // ---- x_one = attn & k_s (binary bf16) -> plane 0 ----
  __syncthreads();   // all plane-0/1 GEMM reads done
  if (ln < 8) {      // one writer per (g, n); tl=0 copies hold full data
    #pragma unroll
    for (int t = 0; t < 4; ++t) {
      unsigned long long w0 = 0ull, w1 = 0ull;
      #pragma unroll
      for (int r = 0; r < 4; ++r) {
        if (((kb0 >> (r * 4 + t)) & 1u) && at[t] != 0.f)
          w0 |= 0x3F80ull << (r * 16);
        if (((kb1 >> (r * 4 + t)) & 1u) && at[t] != 0.f)
          w1 |= 0x3F80ull << (r * 16);
      }
      const int colo = (t * 8 + ln) * 16 + (g & 1) * 8;
      *(unsigned long long*)(lds + LDS_X + (wv * 4 + 0 + (g >> 1)) * XCH + colo) = w0;
      *(unsigned long long*)(lds + LDS_X + (wv * 4 + 2 + (g >> 1)) * XCH + colo) = w1;
    }
  }
  __syncthreads();   // x_one visible

  // ====== proj per o-tile: 2 products {wm, wh} x binary x_one ======
  auto proj_tile = [&](const int ot) {
    f32x4 ap[2];
    ap[0] = ap[1] = (f32x4)0.f;
    #pragma unroll 1
    for (int kk = 0; kk < 8; ++kk) {
      const size_t f0 = (size_t)ot * 8192 + (size_t)kk * 1024 + (size_t)lane * 16;
      const short8 fp0 = *(const short8*)(wp + f0);            // hi
      const short8 fp1 = *(const short8*)(wp + 131072 + f0);   // mid
      __builtin_amdgcn_s_setprio(1);
      #pragma unroll
      for (int nt = 0; nt < 2; ++nt) {
        const short8 b0 = *(const short8*)(lds + LDS_X +
                          (kk * 4 + g) * XCH + (nt * 16 + ln) * 16);
        ap[nt] = MFMA(fp1, b0, ap[nt], 0, 0, 0);
        ap[nt] = MFMA(fp0, b0, ap[nt], 0, 0, 0);
      }
      __builtin_amdgcn_s_setprio(0);
    }
    #pragma unroll
    for (int r = 0; r < 4; ++r) {
      const int o = ot * 16 + g * 4 + r;
      const float inv = p_gamma[o] / sqrtf(p_var[o] + EPSF);
      const float mn = p_mean[o], bt = p_beta[o], pb = proj_b[o];
      const float own0 = ap[0][r], own1 = ap[1][r];
      const float oth0 = __shfl_xor(own0, 8), oth1 = __shfl_xor(own1, 8);
      float pv[4];
      pv[0] = (((tl ? oth0 : own0) + pb) - mn) * inv + bt;
      pv[1] = (((tl ? own0 : oth0) + pb) - mn) * inv + bt;
      pv[2] = (((tl ? oth1 : own1) + pb) - mn) * inv + bt;
      pv[3] = (((tl ? own1 : oth1) + pb) - mn) * inv + bt;
      float sp[4], mg = 1e30f;
      lif4m(pv[0], pv[1], pv[2], pv[3], 1.0f, sp, mg);
      if (__builtin_expect(mg < EPS_R, 0)) {
        float px[4];
        rescue1(proj_w + (size_t)o * CC, lds, n, px);
        #pragma unroll
        for (int t = 0; t < 4; ++t) px[t] = ((px[t] + pb) - mn) * inv + bt;
        float m2 = 1e30f;
        lif4m(px[0], px[1], px[2], px[3], 1.0f, sp, m2);
      }
      if (ln < 8) {
        #pragma unroll
        for (int t = 0; t < 4; ++t)
          out[((size_t)(t * BB + b) * CC + o) * NN + n0 + n] = sp[t];
      }
    }
  };
  proj_tile(wv * 2 + 0);
  proj_tile(wv * 2 + 1);
}

extern "C" void kernel_launch(void* const* d_in, const int* in_sizes, int n_in,
                              void* d_out, int out_size, void* d_ws, size_t ws_size,
                              hipStream_t stream) {
  const float* x       = (const float*)d_in[0];
  const float* q_w     = (const float*)d_in[1];
  const float* q_gamma = (const float*)d_in[2];
  const float* q_beta  = (const float*)d_in[3];
  const float* q_mean  = (const float*)d_in[4];
  const float* q_var   = (const float*)d_in[5];
  const float* k_w     = (const float*)d_in[6];
  const float* k_gamma = (const float*)d_in[7];
  const float* k_beta  = (const float*)d_in[8];
  const float* k_mean  = (const float*)d_in[9];
  const float* k_var   = (const float*)d_in[10];
  const float* proj_w  = (const float*)d_in[11];
  const float* proj_b  = (const float*)d_in[12];
  const float* p_gamma = (const float*)d_in[13];
  const float* p_beta  = (const float*)d_in[14];
  const float* p_mean  = (const float*)d_in[15];
  const float* p_var   = (const float*)d_in[16];
  float* out = (float*)d_out;
  uint16_t* wsp = (uint16_t*)d_ws;   // 1.125 MB split-weight fragment planes

  wsplit2<<<96, 256, 0, stream>>>(q_w, k_w, proj_w, wsp);
  pushpull_mfma11<<<BB * (NN / NT), 512, 0, stream>>>(
      x, q_w, q_gamma, q_beta, q_mean, q_var,
      k_w, k_gamma, k_beta, k_mean, k_var,
      proj_w, proj_b, p_gamma, p_beta, p_mean, p_var, wsp, out);
}